// Round 13
// baseline (1311.132 us; speedup 1.0000x reference)
//
#include <hip/hip_runtime.h>
#include <math.h>

// SpatialGRU persistent-wavefront kernel. B=64, C=16, L=64, R=64, U=64, D=208.
// Round 13: r12 + (1) producer DUAL store (plain -> own-XCD L2 for same-L2
// pollers, sc0sc1 -> MALL for cross-XCD), (2) consumer ALTERNATING poll
// (sc0 fast path / sc0sc1 guaranteed-fresh every other probe; hang-proof),
// (3) v_rcp_f32 for sigmoid/softmax/tanh denominators.
// Phase A: [16 b x 448 kp] = hq[16x224] @ W^T   (bf16 MFMA 16x16x32)
// Phase B: [16 b x 64 u]   = P [16x224] @ U2^T  (P = rr.*hu | x)

typedef short s16x8 __attribute__((ext_vector_type(8)));
typedef float f32x4 __attribute__((ext_vector_type(4)));

#define ASTR 264                 // hq/P row stride (bf16); x slots at 192,224
#define N_WF (32*7*512)          // shorts (32 N-tiles: 12 rr + 16 z + 4 pad)
#define N_UF (4*7*512)           // shorts
#define N_XT (4096*1024)         // shorts
#define POISON 0xFFFFFFFFu       // -NaN; h is always finite

// LDS layout (bytes), 16 batch rows per block
#define OFF_HQ 0                 // [16][ASTR] bf16 = 8448
#define OFF_P  8448              // [16][ASTR] bf16 = 8448
#define OFF_HF 16896             // [3][16][68] f32 = 13056
#define OFF_ZH 29952             // [16][68] f32 = 4352
#define OFF_ZI 34304             // [16][68] f32 = 4352
#define OFF_BA 38656             // [512] f32 = 2048
#define SMEM_BYTES 40704

#define HFv(s,b,u)  HF[(((s)*16 + (b))*68) + (u)]

__device__ __forceinline__ unsigned short f2bf(float v) {
    unsigned int x = __float_as_uint(v);
    unsigned int r = (x + 0x7fffu + ((x >> 16) & 1u)) >> 16;
    return (unsigned short)r;
}
__device__ __forceinline__ unsigned int pack2(float a, float b) {
    return (unsigned int)f2bf(a) | ((unsigned int)f2bf(b) << 16);
}
__device__ __forceinline__ float fast_rcp(float x) {
    float r;
    asm("v_rcp_f32 %0, %1" : "=v"(r) : "v"(x));
    return r;
}
__device__ __forceinline__ float tanh_fast(float x) {
    x = fminf(fmaxf(x, -15.f), 15.f);
    const float e = __expf(2.f * x);
    return (e - 1.f) * fast_rcp(e + 1.f);
}

// ---- producer dual store: plain (own-XCD L2) + sc0sc1 (MALL) ----
__device__ __forceinline__ void st_dual_f32(float* p, float v) {
    asm volatile("global_store_dword %0, %1, off\n\t"
                 "global_store_dword %0, %1, off sc0 sc1"
                 :: "v"(p), "v"(v) : "memory");
}
// ---- poll loads: L2 fast path (sc0) and MALL (sc0 sc1) ----
__device__ __forceinline__ void ld2_llc(const float* p, uint4& A, uint4& B) {
    asm volatile("global_load_dwordx4 %0, %2, off sc0 sc1\n\t"
                 "global_load_dwordx4 %1, %3, off sc0 sc1\n\t"
                 "s_waitcnt vmcnt(0)"
                 : "=&v"(A), "=&v"(B) : "v"(p), "v"(p + 4) : "memory");
}
__device__ __forceinline__ void ld2_l2(const float* p, uint4& A, uint4& B) {
    asm volatile("global_load_dwordx4 %0, %2, off sc0\n\t"
                 "global_load_dwordx4 %1, %3, off sc0\n\t"
                 "s_waitcnt vmcnt(0)"
                 : "=&v"(A), "=&v"(B) : "v"(p), "v"(p + 4) : "memory");
}

// ---- prep: pack weights into MFMA B-fragment lane order ----
// nt 0..11 = rr rows kp=nt*16+c. nt 12..27: g=(nt-12)>>2 (gate i,l,t,d),
// q=(nt-12)&3, u=q*16+c -> wz_w row g*64+u. nt 28..31: zeros.
__global__ __launch_bounds__(256) void prep_pack(
    const float* __restrict__ wr_w, const float* __restrict__ wr_b,
    const float* __restrict__ wz_w, const float* __restrict__ wz_b,
    const float* __restrict__ wij_w, const float* __restrict__ U_w,
    unsigned short* __restrict__ WF, unsigned short* __restrict__ UF,
    float* __restrict__ BAf)
{
    int idx = blockIdx.x * 256 + threadIdx.x;
    if (idx < 32*7*64) {
        int frag = idx >> 6, lane = idx & 63;
        int nt = frag / 7, ks = frag % 7;
        int c  = lane & 15;
        int kb = ks*32 + ((lane >> 4) << 3);
        #pragma unroll
        for (int e = 0; e < 8; ++e) {
            int k = kb + e;
            float v = 0.f;
            if (k < 208) {
                if (nt < 12) v = wr_w[(nt*16 + c)*208 + k];
                else if (nt < 28) {
                    int g = (nt - 12) >> 2, q = (nt - 12) & 3;
                    v = wz_w[(g*64 + q*16 + c)*208 + k];
                }
            }
            WF[idx*8 + e] = f2bf(v);
        }
        return;
    }
    idx -= 32*7*64;
    if (idx < 4*7*64) {
        int frag = idx >> 6, lane = idx & 63;
        int t2 = frag / 7, ks = frag % 7;
        int u = t2*16 + (lane & 15);
        int kb = ks*32 + ((lane >> 4) << 3);
        #pragma unroll
        for (int e = 0; e < 8; ++e) {
            int k = kb + e;
            float v = 0.f;
            if (k < 192) v = U_w[u*192 + k];
            else if (k < 208) v = wij_w[u*16 + (k - 192)];
            UF[idx*8 + e] = f2bf(v);
        }
        return;
    }
    idx -= 4*7*64;
    if (idx < 512) {
        int nt = idx >> 4, c = idx & 15;
        float v = 0.f;
        if (nt < 12) v = wr_b[nt*16 + c];
        else if (nt < 28) {
            int g = (nt - 12) >> 2, q = (nt - 12) & 3;
            v = wz_b[g*64 + q*16 + c];
        }
        BAf[idx] = v;
    }
}

// ---- prep: transpose inputs (B,C,L,R) -> XT[(l,r)][(b,c)] bf16 ----
__global__ __launch_bounds__(256) void xpose(const float* __restrict__ inp,
                                             unsigned short* __restrict__ XT)
{
    __shared__ float tile[32][33];
    int bi = blockIdx.x;   // lr / 32
    int bj = blockIdx.y;   // bc / 32
    int tx = threadIdx.x & 31, ty = threadIdx.x >> 5;
    #pragma unroll
    for (int yy = 0; yy < 4; ++yy) {
        int bc = bj*32 + ty*4 + yy;
        tile[ty*4 + yy][tx] = inp[bc*4096 + bi*32 + tx];
    }
    __syncthreads();
    #pragma unroll
    for (int yy = 0; yy < 4; ++yy) {
        int lr = bi*32 + ty*4 + yy;
        XT[lr*1024 + bj*32 + tx] = f2bf(tile[tx][ty*4 + yy]);
    }
}

// ---- persistent wavefront ----
__global__ __launch_bounds__(512, 2) void gru_persist(
    const unsigned short* __restrict__ WF,
    const unsigned short* __restrict__ UF,
    const float* __restrict__ BAf,
    const unsigned short* __restrict__ XT,
    const float* __restrict__ wij_b,
    float* __restrict__ Hout,          // [l][r][b(64)][u(64)] fp32, poisoned
    float* __restrict__ out)
{
    extern __shared__ char smem[];
    unsigned short* hq_s = (unsigned short*)(smem + OFF_HQ);
    unsigned short* P_s  = (unsigned short*)(smem + OFF_P);
    float* HF   = (float*)(smem + OFF_HF);
    float* ZH_s = (float*)(smem + OFF_ZH);
    float* ZI_s = (float*)(smem + OFF_ZI);
    float* BA_l = (float*)(smem + OFF_BA);

    const int tid = threadIdx.x;
    const int qq = blockIdx.x >> 6;                               // batch quarter
    const int i  = blockIdx.x & 63;
    const int l  = ((i & 7) << 3) | (i >> 3);                     // XCD swizzle
    const int b0 = qq * 16;

    // init: hq/P zero, HF zero, bias to LDS
    {
        unsigned int* hqu = (unsigned int*)hq_s;
        unsigned int* pu  = (unsigned int*)P_s;
        for (int k = tid; k < 16*ASTR/2; k += 512) { hqu[k] = 0u; pu[k] = 0u; }
        for (int k = tid; k < 3*16*68; k += 512) HF[k] = 0.f;
        BA_l[tid] = BAf[tid];
    }

    const int wv = tid >> 6, lane = tid & 63;
    const int col = lane & 15, rowq = (lane >> 4) << 2;
    // poll/stage ownership: 128 act lanes, (sb, su) chunk of 8 floats
    const bool act = (tid & 3) == 0;
    const int sb = tid >> 5;                 // 0..15 local batch row
    const int su = ((tid >> 2) & 7) * 8;     // 0..56

    // tile assignment: waves 0-3 -> 3 rr tiles + pad; waves 4-7 -> 4 gates
    int ntj[4];
    #pragma unroll
    for (int j = 0; j < 4; ++j)
        ntj[j] = (wv < 4) ? ((j < 3) ? wv*3 + j : 28 + wv)
                          : (12 + (wv - 4) + 4*j);

    // ---- load weights into registers ONCE ----
    s16x8 wa[4][7];
    #pragma unroll
    for (int j = 0; j < 4; ++j)
        #pragma unroll
        for (int ks = 0; ks < 7; ++ks) {
            wa[j][ks] = *(const s16x8*)&WF[((ntj[j]*7 + ks)*64 + lane)*8];
            asm volatile("" : "+v"(wa[j][ks]));
        }
    s16x8 ub[7];
    if (wv < 4) {
        #pragma unroll
        for (int ks = 0; ks < 7; ++ks)
            ub[ks] = *(const s16x8*)&UF[((wv*7 + ks)*64 + lane)*8];
    }
    // stage x(l, 0) into parity slot 0 (cols 192-224)
    if (tid < 32) {
        uint4 xv = *(const uint4*)&XT[((size_t)(l*64))*1024 + (b0 + (tid>>1))*16 + (tid&1)*8];
        *(uint4*)&hq_s[(tid>>1)*ASTR + 192 + (tid&1)*8] = xv;
    }
    __syncthreads();

    #pragma unroll 1
    for (int r = 0; r < 64; ++r) {
        const int xcol  = 192 + ((r & 1) << 5);        // this step's x slot
        const int xcoln = 192 + (((r + 1) & 1) << 5);  // next step's x slot

        // ---- x prefetch for r+1 (waves 4-7, first 32 lanes) ----
        uint4 xpref;
        const int t2 = tid - 256;
        const bool xpl = (t2 >= 0) && (t2 < 32) && (r < 63);
        if (xpl)
            xpref = *(const uint4*)&XT[((size_t)(l*64 + r + 1))*1024
                                       + (b0 + (t2 >> 1))*16 + (t2 & 1)*8];

        // ---- phase 1: preMFMA — hl (ks2,3), hd (ks4,5), x (slot xcol) ----
        f32x4 acc[4];
        #pragma unroll
        for (int j = 0; j < 4; ++j) acc[j] = (f32x4){0.f, 0.f, 0.f, 0.f};
        #pragma unroll
        for (int ks = 2; ks < 6; ++ks) {
            s16x8 af = *(const s16x8*)&hq_s[col*ASTR + ks*32 + (rowq << 1)];
            #pragma unroll
            for (int j = 0; j < 4; ++j)
                acc[j] = __builtin_amdgcn_mfma_f32_16x16x32_bf16(af, wa[j][ks], acc[j], 0, 0, 0);
        }
        {
            s16x8 af = *(const s16x8*)&hq_s[col*ASTR + xcol + (rowq << 1)];
            #pragma unroll
            for (int j = 0; j < 4; ++j)
                acc[j] = __builtin_amdgcn_mfma_f32_16x16x32_bf16(af, wa[j][6], acc[j], 0, 0, 0);
        }

        // ---- phase 2: spin on ht chunk (l-1, r); alternating scope ----
        if (act) {
            f32x4 a = (f32x4){0,0,0,0}, b4 = (f32x4){0,0,0,0};
            if (l > 0) {
                const float* pp = Hout + ((size_t)((l-1)*64 + r))*4096 + (b0 + sb)*64 + su;
                uint4 A, B;
                int it = 0;
                for (;;) {
                    // even: L2 fast path (fresh if same-XCD producer's plain
                    // store hit our L2); odd: MALL probe (always fresh)
                    if (it & 1) ld2_llc(pp, A, B);
                    else        ld2_l2(pp, A, B);
                    if (!(A.x == POISON || A.y == POISON || A.z == POISON || A.w == POISON ||
                          B.x == POISON || B.y == POISON || B.z == POISON || B.w == POISON)) break;
                    if (++it > 6) __builtin_amdgcn_s_sleep(2);
                }
                a[0] = __uint_as_float(A.x); a[1] = __uint_as_float(A.y);
                a[2] = __uint_as_float(A.z); a[3] = __uint_as_float(A.w);
                b4[0] = __uint_as_float(B.x); b4[1] = __uint_as_float(B.y);
                b4[2] = __uint_as_float(B.z); b4[3] = __uint_as_float(B.w);
            }
            *(f32x4*)&HFv(0, sb, su)     = a;
            *(f32x4*)&HFv(0, sb, su + 4) = b4;
            uint4 htp;
            htp.x = pack2(a[0], a[1]);   htp.y = pack2(a[2], a[3]);
            htp.z = pack2(b4[0], b4[1]); htp.w = pack2(b4[2], b4[3]);
            *(uint4*)&hq_s[sb*ASTR + su] = htp;              // ht (cols 0-64)
        }
        __syncthreads();

        // ---- phase 3: postMFMA ks0,1 (ht) + activation ----
        #pragma unroll
        for (int ks = 0; ks < 2; ++ks) {
            s16x8 af = *(const s16x8*)&hq_s[col*ASTR + ks*32 + (rowq << 1)];
            #pragma unroll
            for (int j = 0; j < 4; ++j)
                acc[j] = __builtin_amdgcn_mfma_f32_16x16x32_bf16(af, wa[j][ks], acc[j], 0, 0, 0);
        }
        if (wv < 4) {
            // rr: P[b][kp] = sigmoid(val) * hu[kp]; hu = [hl|ht|hd] = HF{1,0,2}
            #pragma unroll
            for (int j = 0; j < 3; ++j) {
                const int nt = wv*3 + j;
                const int kp = nt*16 + col;
                const float bias = BA_l[kp];
                const int sel = nt >> 2;
                const float* Hsel = HF + ((sel == 0) ? 1 : (sel == 1) ? 0 : 2)*16*68;
                const int uoff = kp & 63;
                #pragma unroll
                for (int reg = 0; reg < 4; ++reg) {
                    const int b = rowq + reg;
                    const float val = acc[j][reg] + bias;
                    const float rr = fast_rcp(1.f + __expf(-val));
                    P_s[b*ASTR + kp] = f2bf(rr * Hsel[b*68 + uoff]);
                }
            }
        } else {
            // z: lane holds all 4 gates of (b, uz) in acc[0..3][reg]
            const int uz = (wv - 4)*16 + col;
            const float bi = BA_l[(12 + (wv-4) +  0)*16 + col];
            const float bl = BA_l[(12 + (wv-4) +  4)*16 + col];
            const float bt = BA_l[(12 + (wv-4) +  8)*16 + col];
            const float bd = BA_l[(12 + (wv-4) + 12)*16 + col];
            #pragma unroll
            for (int reg = 0; reg < 4; ++reg) {
                const int b = rowq + reg;
                const float vi = acc[0][reg] + bi;
                const float vl = acc[1][reg] + bl;
                const float vt = acc[2][reg] + bt;
                const float vd = acc[3][reg] + bd;
                const float mx = fmaxf(fmaxf(vi, vl), fmaxf(vt, vd));
                const float ei = __expf(vi - mx);
                const float el = __expf(vl - mx);
                const float et = __expf(vt - mx);
                const float ed = __expf(vd - mx);
                const float inv = fast_rcp(ei + el + et + ed);
                const float hl = HFv(1, b, uz);
                const float ht = HFv(0, b, uz);
                const float hd = HFv(2, b, uz);
                ZI_s[b*68 + uz] = ei * inv;
                ZH_s[b*68 + uz] = (el*hl + et*ht + ed*hd) * inv;
            }
        }
        __syncthreads();   // P, ZH, ZI complete

        // ---- phase 4: phase B (waves 0-3) || shift+x-writeback (waves 4-7) ----
        if (wv < 4) {
            f32x4 a2a = (f32x4){0,0,0,0}, a2b = (f32x4){0,0,0,0};
            #pragma unroll
            for (int ks = 0; ks < 6; ks += 2) {
                s16x8 x0 = *(const s16x8*)&P_s[col*ASTR + ks*32 + (rowq << 1)];
                s16x8 x1 = *(const s16x8*)&P_s[col*ASTR + (ks+1)*32 + (rowq << 1)];
                a2a = __builtin_amdgcn_mfma_f32_16x16x32_bf16(x0, ub[ks],   a2a, 0, 0, 0);
                a2b = __builtin_amdgcn_mfma_f32_16x16x32_bf16(x1, ub[ks+1], a2b, 0, 0, 0);
            }
            {
                s16x8 xf = *(const s16x8*)&hq_s[col*ASTR + xcol + (rowq << 1)];
                a2a = __builtin_amdgcn_mfma_f32_16x16x32_bf16(xf, ub[6], a2a, 0, 0, 0);
            }
            const f32x4 asum = a2a + a2b;
            const int u = wv*16 + col;
            const float wb = wij_b[u];
            float* Hrow = Hout + ((size_t)(l*64 + r))*4096;
            #pragma unroll
            for (int reg = 0; reg < 4; ++reg) {
                const int b = rowq + reg;
                const float hn = tanh_fast(asum[reg] + wb);
                const float h = ZH_s[b*68 + u] + ZI_s[b*68 + u] * hn;
                HFv(1, b, u) = h;                                   // hl (f32)
                hq_s[b*ASTR + 64 + u] = f2bf(h);                    // hl (bf16)
                if (l < 63) st_dual_f32(&Hrow[(b0 + b)*64 + u], h); // L2 + MALL
                else if (r == 63) out[(b0 + b)*64 + u] = h;
            }
            // no store drain: poison protocol checks each word independently
        } else {
            const int bb = t2 >> 4, jj = t2 & 15;
            // hd <- ht (f32 mirror + bf16 tile)
            *(f32x4*)&HFv(2, bb, jj*4) = *(const f32x4*)&HFv(0, bb, jj*4);
            if (jj < 8)
                *(uint4*)&hq_s[bb*ASTR + 128 + jj*8] =
                    *(const uint4*)&hq_s[bb*ASTR + jj*8];
            // x(r+1) into the other parity slot
            if (xpl)
                *(uint4*)&hq_s[(t2 >> 1)*ASTR + xcoln + (t2 & 1)*8] = xpref;
        }
        __syncthreads();
    }
}

extern "C" void kernel_launch(void* const* d_in, const int* in_sizes, int n_in,
                              void* d_out, int out_size, void* d_ws, size_t ws_size,
                              hipStream_t stream)
{
    const float* inp   = (const float*)d_in[0];
    const float* wr_w  = (const float*)d_in[1];
    const float* wr_b  = (const float*)d_in[2];
    const float* wz_w  = (const float*)d_in[3];
    const float* wz_b  = (const float*)d_in[4];
    const float* wij_w = (const float*)d_in[5];
    const float* wij_b = (const float*)d_in[6];
    const float* U_w   = (const float*)d_in[7];
    float* out = (float*)d_out;

    unsigned short* WF = (unsigned short*)d_ws;
    unsigned short* UF = WF + N_WF;
    unsigned short* XT = UF + N_UF;
    float* fbase = (float*)(XT + N_XT);
    float* BAf   = fbase;                          // 512 floats
    float* Hout  = fbase + 512;                    // 64*64*4096 floats (64 MB)

    // poison the H buffer: 0xFF bytes = -NaN dwords (h is always finite)
    hipMemsetAsync(Hout, 0xFF, (size_t)64*64*4096*sizeof(float), stream);
    prep_pack<<<66, 256, 0, stream>>>(wr_w, wr_b, wz_w, wz_b, wij_w, U_w, WF, UF, BAf);
    xpose<<<dim3(128, 32), 256, 0, stream>>>(inp, XT);

    gru_persist<<<256, 512, SMEM_BYTES, stream>>>(WF, UF, BAf, XT, wij_b, Hout, out);
}

// Round 15
// 321.143 us; speedup vs baseline: 4.0827x; 4.0827x over previous
//
#include <hip/hip_runtime.h>
#include <math.h>

// SpatialGRU persistent-wavefront kernel. B=64, C=16, L=64, R=64, U=64, D=208.
// Round 15: STRICT revert to r12 (353 us, proven) + v_rcp_f32 denominators.
// Locked lessons: ONE sc0sc1 store per value; EVERY poll at the coherence
// point, load+waitcnt+check INSIDE one data-dependent asm pattern (no
// split-issue polling — compiler reorders register reads past waitcnt asm).
// Phase A: [16 b x 448 kp] = hq[16x224] @ W^T   (bf16 MFMA 16x16x32)
// Phase B: [16 b x 64 u]   = P [16x224] @ U2^T  (P = rr.*hu | x)

typedef short s16x8 __attribute__((ext_vector_type(8)));
typedef float f32x4 __attribute__((ext_vector_type(4)));

#define ASTR 264                 // hq/P row stride (bf16); x slots at 192,224
#define N_WF (32*7*512)          // shorts (32 N-tiles: 12 rr + 16 z + 4 pad)
#define N_UF (4*7*512)           // shorts
#define N_XT (4096*1024)         // shorts
#define POISON 0xFFFFFFFFu       // -NaN; h is always finite

// LDS layout (bytes), 16 batch rows per block
#define OFF_HQ 0                 // [16][ASTR] bf16 = 8448
#define OFF_P  8448              // [16][ASTR] bf16 = 8448
#define OFF_HF 16896             // [3][16][68] f32 = 13056
#define OFF_ZH 29952             // [16][68] f32 = 4352
#define OFF_ZI 34304             // [16][68] f32 = 4352
#define OFF_BA 38656             // [512] f32 = 2048
#define SMEM_BYTES 40704

#define HFv(s,b,u)  HF[(((s)*16 + (b))*68) + (u)]

__device__ __forceinline__ unsigned short f2bf(float v) {
    unsigned int x = __float_as_uint(v);
    unsigned int r = (x + 0x7fffu + ((x >> 16) & 1u)) >> 16;
    return (unsigned short)r;
}
__device__ __forceinline__ unsigned int pack2(float a, float b) {
    return (unsigned int)f2bf(a) | ((unsigned int)f2bf(b) << 16);
}
__device__ __forceinline__ float fast_rcp(float x) {
    float r;
    asm("v_rcp_f32 %0, %1" : "=v"(r) : "v"(x));
    return r;
}
__device__ __forceinline__ float tanh_fast(float x) {
    x = fminf(fmaxf(x, -15.f), 15.f);
    const float e = __expf(2.f * x);
    return (e - 1.f) * fast_rcp(e + 1.f);
}

// ---- LLC write-through payload store (coherence point) ----
__device__ __forceinline__ void st_llc_f32(float* p, float v) {
    asm volatile("global_store_dword %0, %1, off sc0 sc1" :: "v"(p), "v"(v) : "memory");
}
// ---- LLC poll load (coherence point, wait inside the asm block) ----
__device__ __forceinline__ void ld2_llc(const float* p, uint4& A, uint4& B) {
    asm volatile("global_load_dwordx4 %0, %2, off sc0 sc1\n\t"
                 "global_load_dwordx4 %1, %3, off sc0 sc1\n\t"
                 "s_waitcnt vmcnt(0)"
                 : "=&v"(A), "=&v"(B) : "v"(p), "v"(p + 4) : "memory");
}

// ---- prep: pack weights into MFMA B-fragment lane order ----
// nt 0..11 = rr rows kp=nt*16+c. nt 12..27: g=(nt-12)>>2 (gate i,l,t,d),
// q=(nt-12)&3, u=q*16+c -> wz_w row g*64+u. nt 28..31: zeros.
__global__ __launch_bounds__(256) void prep_pack(
    const float* __restrict__ wr_w, const float* __restrict__ wr_b,
    const float* __restrict__ wz_w, const float* __restrict__ wz_b,
    const float* __restrict__ wij_w, const float* __restrict__ U_w,
    unsigned short* __restrict__ WF, unsigned short* __restrict__ UF,
    float* __restrict__ BAf)
{
    int idx = blockIdx.x * 256 + threadIdx.x;
    if (idx < 32*7*64) {
        int frag = idx >> 6, lane = idx & 63;
        int nt = frag / 7, ks = frag % 7;
        int c  = lane & 15;
        int kb = ks*32 + ((lane >> 4) << 3);
        #pragma unroll
        for (int e = 0; e < 8; ++e) {
            int k = kb + e;
            float v = 0.f;
            if (k < 208) {
                if (nt < 12) v = wr_w[(nt*16 + c)*208 + k];
                else if (nt < 28) {
                    int g = (nt - 12) >> 2, q = (nt - 12) & 3;
                    v = wz_w[(g*64 + q*16 + c)*208 + k];
                }
            }
            WF[idx*8 + e] = f2bf(v);
        }
        return;
    }
    idx -= 32*7*64;
    if (idx < 4*7*64) {
        int frag = idx >> 6, lane = idx & 63;
        int t2 = frag / 7, ks = frag % 7;
        int u = t2*16 + (lane & 15);
        int kb = ks*32 + ((lane >> 4) << 3);
        #pragma unroll
        for (int e = 0; e < 8; ++e) {
            int k = kb + e;
            float v = 0.f;
            if (k < 192) v = U_w[u*192 + k];
            else if (k < 208) v = wij_w[u*16 + (k - 192)];
            UF[idx*8 + e] = f2bf(v);
        }
        return;
    }
    idx -= 4*7*64;
    if (idx < 512) {
        int nt = idx >> 4, c = idx & 15;
        float v = 0.f;
        if (nt < 12) v = wr_b[nt*16 + c];
        else if (nt < 28) {
            int g = (nt - 12) >> 2, q = (nt - 12) & 3;
            v = wz_b[g*64 + q*16 + c];
        }
        BAf[idx] = v;
    }
}

// ---- prep: transpose inputs (B,C,L,R) -> XT[(l,r)][(b,c)] bf16 ----
__global__ __launch_bounds__(256) void xpose(const float* __restrict__ inp,
                                             unsigned short* __restrict__ XT)
{
    __shared__ float tile[32][33];
    int bi = blockIdx.x;   // lr / 32
    int bj = blockIdx.y;   // bc / 32
    int tx = threadIdx.x & 31, ty = threadIdx.x >> 5;
    #pragma unroll
    for (int yy = 0; yy < 4; ++yy) {
        int bc = bj*32 + ty*4 + yy;
        tile[ty*4 + yy][tx] = inp[bc*4096 + bi*32 + tx];
    }
    __syncthreads();
    #pragma unroll
    for (int yy = 0; yy < 4; ++yy) {
        int lr = bi*32 + ty*4 + yy;
        XT[lr*1024 + bj*32 + tx] = f2bf(tile[tx][ty*4 + yy]);
    }
}

// ---- persistent wavefront ----
__global__ __launch_bounds__(512, 2) void gru_persist(
    const unsigned short* __restrict__ WF,
    const unsigned short* __restrict__ UF,
    const float* __restrict__ BAf,
    const unsigned short* __restrict__ XT,
    const float* __restrict__ wij_b,
    float* __restrict__ Hout,          // [l][r][b(64)][u(64)] fp32, poisoned
    float* __restrict__ out)
{
    extern __shared__ char smem[];
    unsigned short* hq_s = (unsigned short*)(smem + OFF_HQ);
    unsigned short* P_s  = (unsigned short*)(smem + OFF_P);
    float* HF   = (float*)(smem + OFF_HF);
    float* ZH_s = (float*)(smem + OFF_ZH);
    float* ZI_s = (float*)(smem + OFF_ZI);
    float* BA_l = (float*)(smem + OFF_BA);

    const int tid = threadIdx.x;
    const int qq = blockIdx.x >> 6;                               // batch quarter
    const int i  = blockIdx.x & 63;
    const int l  = ((i & 7) << 3) | (i >> 3);                     // XCD swizzle
    const int b0 = qq * 16;

    // init: hq/P zero, HF zero, bias to LDS
    {
        unsigned int* hqu = (unsigned int*)hq_s;
        unsigned int* pu  = (unsigned int*)P_s;
        for (int k = tid; k < 16*ASTR/2; k += 512) { hqu[k] = 0u; pu[k] = 0u; }
        for (int k = tid; k < 3*16*68; k += 512) HF[k] = 0.f;
        BA_l[tid] = BAf[tid];
    }

    const int wv = tid >> 6, lane = tid & 63;
    const int col = lane & 15, rowq = (lane >> 4) << 2;
    // poll/stage ownership: 128 act lanes, (sb, su) chunk of 8 floats
    const bool act = (tid & 3) == 0;
    const int sb = tid >> 5;                 // 0..15 local batch row
    const int su = ((tid >> 2) & 7) * 8;     // 0..56

    // tile assignment: waves 0-3 -> 3 rr tiles + pad; waves 4-7 -> 4 gates
    int ntj[4];
    #pragma unroll
    for (int j = 0; j < 4; ++j)
        ntj[j] = (wv < 4) ? ((j < 3) ? wv*3 + j : 28 + wv)
                          : (12 + (wv - 4) + 4*j);

    // ---- load weights into registers ONCE ----
    s16x8 wa[4][7];
    #pragma unroll
    for (int j = 0; j < 4; ++j)
        #pragma unroll
        for (int ks = 0; ks < 7; ++ks) {
            wa[j][ks] = *(const s16x8*)&WF[((ntj[j]*7 + ks)*64 + lane)*8];
            asm volatile("" : "+v"(wa[j][ks]));
        }
    s16x8 ub[7];
    if (wv < 4) {
        #pragma unroll
        for (int ks = 0; ks < 7; ++ks)
            ub[ks] = *(const s16x8*)&UF[((wv*7 + ks)*64 + lane)*8];
    }
    // stage x(l, 0) into parity slot 0 (cols 192-224)
    if (tid < 32) {
        uint4 xv = *(const uint4*)&XT[((size_t)(l*64))*1024 + (b0 + (tid>>1))*16 + (tid&1)*8];
        *(uint4*)&hq_s[(tid>>1)*ASTR + 192 + (tid&1)*8] = xv;
    }
    __syncthreads();

    #pragma unroll 1
    for (int r = 0; r < 64; ++r) {
        const int xcol  = 192 + ((r & 1) << 5);        // this step's x slot
        const int xcoln = 192 + (((r + 1) & 1) << 5);  // next step's x slot

        // ---- x prefetch for r+1 (waves 4-7, first 32 lanes) ----
        uint4 xpref;
        const int t2 = tid - 256;
        const bool xpl = (t2 >= 0) && (t2 < 32) && (r < 63);
        if (xpl)
            xpref = *(const uint4*)&XT[((size_t)(l*64 + r + 1))*1024
                                       + (b0 + (t2 >> 1))*16 + (t2 & 1)*8];

        // ---- phase 1: preMFMA — hl (ks2,3), hd (ks4,5), x (slot xcol) ----
        f32x4 acc[4];
        #pragma unroll
        for (int j = 0; j < 4; ++j) acc[j] = (f32x4){0.f, 0.f, 0.f, 0.f};
        #pragma unroll
        for (int ks = 2; ks < 6; ++ks) {
            s16x8 af = *(const s16x8*)&hq_s[col*ASTR + ks*32 + (rowq << 1)];
            #pragma unroll
            for (int j = 0; j < 4; ++j)
                acc[j] = __builtin_amdgcn_mfma_f32_16x16x32_bf16(af, wa[j][ks], acc[j], 0, 0, 0);
        }
        {
            s16x8 af = *(const s16x8*)&hq_s[col*ASTR + xcol + (rowq << 1)];
            #pragma unroll
            for (int j = 0; j < 4; ++j)
                acc[j] = __builtin_amdgcn_mfma_f32_16x16x32_bf16(af, wa[j][6], acc[j], 0, 0, 0);
        }

        // ---- phase 2: spin on ht chunk (l-1, r) at the COHERENCE POINT ----
        if (act) {
            f32x4 a = (f32x4){0,0,0,0}, b4 = (f32x4){0,0,0,0};
            if (l > 0) {
                const float* pp = Hout + ((size_t)((l-1)*64 + r))*4096 + (b0 + sb)*64 + su;
                uint4 A, B;
                int it = 0;
                for (;;) {
                    ld2_llc(pp, A, B);
                    if (!(A.x == POISON || A.y == POISON || A.z == POISON || A.w == POISON ||
                          B.x == POISON || B.y == POISON || B.z == POISON || B.w == POISON)) break;
                    if (++it > 3) __builtin_amdgcn_s_sleep(1);
                }
                a[0] = __uint_as_float(A.x); a[1] = __uint_as_float(A.y);
                a[2] = __uint_as_float(A.z); a[3] = __uint_as_float(A.w);
                b4[0] = __uint_as_float(B.x); b4[1] = __uint_as_float(B.y);
                b4[2] = __uint_as_float(B.z); b4[3] = __uint_as_float(B.w);
            }
            *(f32x4*)&HFv(0, sb, su)     = a;
            *(f32x4*)&HFv(0, sb, su + 4) = b4;
            uint4 htp;
            htp.x = pack2(a[0], a[1]);   htp.y = pack2(a[2], a[3]);
            htp.z = pack2(b4[0], b4[1]); htp.w = pack2(b4[2], b4[3]);
            *(uint4*)&hq_s[sb*ASTR + su] = htp;              // ht (cols 0-64)
        }
        __syncthreads();

        // ---- phase 3: postMFMA ks0,1 (ht) + activation ----
        #pragma unroll
        for (int ks = 0; ks < 2; ++ks) {
            s16x8 af = *(const s16x8*)&hq_s[col*ASTR + ks*32 + (rowq << 1)];
            #pragma unroll
            for (int j = 0; j < 4; ++j)
                acc[j] = __builtin_amdgcn_mfma_f32_16x16x32_bf16(af, wa[j][ks], acc[j], 0, 0, 0);
        }
        if (wv < 4) {
            // rr: P[b][kp] = sigmoid(val) * hu[kp]; hu = [hl|ht|hd] = HF{1,0,2}
            #pragma unroll
            for (int j = 0; j < 3; ++j) {
                const int nt = wv*3 + j;
                const int kp = nt*16 + col;
                const float bias = BA_l[kp];
                const int sel = nt >> 2;
                const float* Hsel = HF + ((sel == 0) ? 1 : (sel == 1) ? 0 : 2)*16*68;
                const int uoff = kp & 63;
                #pragma unroll
                for (int reg = 0; reg < 4; ++reg) {
                    const int b = rowq + reg;
                    const float val = acc[j][reg] + bias;
                    const float rr = fast_rcp(1.f + __expf(-val));
                    P_s[b*ASTR + kp] = f2bf(rr * Hsel[b*68 + uoff]);
                }
            }
        } else {
            // z: lane holds all 4 gates of (b, uz) in acc[0..3][reg]
            const int uz = (wv - 4)*16 + col;
            const float bi = BA_l[(12 + (wv-4) +  0)*16 + col];
            const float bl = BA_l[(12 + (wv-4) +  4)*16 + col];
            const float bt = BA_l[(12 + (wv-4) +  8)*16 + col];
            const float bd = BA_l[(12 + (wv-4) + 12)*16 + col];
            #pragma unroll
            for (int reg = 0; reg < 4; ++reg) {
                const int b = rowq + reg;
                const float vi = acc[0][reg] + bi;
                const float vl = acc[1][reg] + bl;
                const float vt = acc[2][reg] + bt;
                const float vd = acc[3][reg] + bd;
                const float mx = fmaxf(fmaxf(vi, vl), fmaxf(vt, vd));
                const float ei = __expf(vi - mx);
                const float el = __expf(vl - mx);
                const float et = __expf(vt - mx);
                const float ed = __expf(vd - mx);
                const float inv = fast_rcp(ei + el + et + ed);
                const float hl = HFv(1, b, uz);
                const float ht = HFv(0, b, uz);
                const float hd = HFv(2, b, uz);
                ZI_s[b*68 + uz] = ei * inv;
                ZH_s[b*68 + uz] = (el*hl + et*ht + ed*hd) * inv;
            }
        }
        __syncthreads();   // P, ZH, ZI complete

        // ---- phase 4: phase B (waves 0-3) || shift+x-writeback (waves 4-7) ----
        if (wv < 4) {
            f32x4 a2a = (f32x4){0,0,0,0}, a2b = (f32x4){0,0,0,0};
            #pragma unroll
            for (int ks = 0; ks < 6; ks += 2) {
                s16x8 x0 = *(const s16x8*)&P_s[col*ASTR + ks*32 + (rowq << 1)];
                s16x8 x1 = *(const s16x8*)&P_s[col*ASTR + (ks+1)*32 + (rowq << 1)];
                a2a = __builtin_amdgcn_mfma_f32_16x16x32_bf16(x0, ub[ks],   a2a, 0, 0, 0);
                a2b = __builtin_amdgcn_mfma_f32_16x16x32_bf16(x1, ub[ks+1], a2b, 0, 0, 0);
            }
            {
                s16x8 xf = *(const s16x8*)&hq_s[col*ASTR + xcol + (rowq << 1)];
                a2a = __builtin_amdgcn_mfma_f32_16x16x32_bf16(xf, ub[6], a2a, 0, 0, 0);
            }
            const f32x4 asum = a2a + a2b;
            const int u = wv*16 + col;
            const float wb = wij_b[u];
            float* Hrow = Hout + ((size_t)(l*64 + r))*4096;
            #pragma unroll
            for (int reg = 0; reg < 4; ++reg) {
                const int b = rowq + reg;
                const float hn = tanh_fast(asum[reg] + wb);
                const float h = ZH_s[b*68 + u] + ZI_s[b*68 + u] * hn;
                HFv(1, b, u) = h;                                   // hl (f32)
                hq_s[b*ASTR + 64 + u] = f2bf(h);                    // hl (bf16)
                if (l < 63) st_llc_f32(&Hrow[(b0 + b)*64 + u], h);  // write-through
                else if (r == 63) out[(b0 + b)*64 + u] = h;
            }
            // no store drain: poison protocol checks each word independently
        } else {
            const int bb = t2 >> 4, jj = t2 & 15;
            // hd <- ht (f32 mirror + bf16 tile)
            *(f32x4*)&HFv(2, bb, jj*4) = *(const f32x4*)&HFv(0, bb, jj*4);
            if (jj < 8)
                *(uint4*)&hq_s[bb*ASTR + 128 + jj*8] =
                    *(const uint4*)&hq_s[bb*ASTR + jj*8];
            // x(r+1) into the other parity slot
            if (xpl)
                *(uint4*)&hq_s[(t2 >> 1)*ASTR + xcoln + (t2 & 1)*8] = xpref;
        }
        __syncthreads();
    }
}

extern "C" void kernel_launch(void* const* d_in, const int* in_sizes, int n_in,
                              void* d_out, int out_size, void* d_ws, size_t ws_size,
                              hipStream_t stream)
{
    const float* inp   = (const float*)d_in[0];
    const float* wr_w  = (const float*)d_in[1];
    const float* wr_b  = (const float*)d_in[2];
    const float* wz_w  = (const float*)d_in[3];
    const float* wz_b  = (const float*)d_in[4];
    const float* wij_w = (const float*)d_in[5];
    const float* wij_b = (const float*)d_in[6];
    const float* U_w   = (const float*)d_in[7];
    float* out = (float*)d_out;

    unsigned short* WF = (unsigned short*)d_ws;
    unsigned short* UF = WF + N_WF;
    unsigned short* XT = UF + N_UF;
    float* fbase = (float*)(XT + N_XT);
    float* BAf   = fbase;                          // 512 floats
    float* Hout  = fbase + 512;                    // 64*64*4096 floats (64 MB)

    // poison the H buffer: 0xFF bytes = -NaN dwords (h is always finite)
    hipMemsetAsync(Hout, 0xFF, (size_t)64*64*4096*sizeof(float), stream);
    prep_pack<<<66, 256, 0, stream>>>(wr_w, wr_b, wz_w, wz_b, wij_w, U_w, WF, UF, BAf);
    xpose<<<dim3(128, 32), 256, 0, stream>>>(inp, XT);

    gru_persist<<<256, 512, SMEM_BYTES, stream>>>(WF, UF, BAf, XT, wij_b, Hout, out);
}